// Round 5
// baseline (2024.172 us; speedup 1.0000x reference)
//
#include <hip/hip_runtime.h>
#include <math.h>

#define N_NODES 10000
#define N_EDGES 160000
#define BATCH 32
#define HLEN 12
#define KORD 25
#define G1 32
#define NCLS 10
#define BH 384   /* BATCH*HLEN */
#define BG 1024  /* BATCH*G1  */
#define NQ 8     /* BH split into 8 slices of 48 floats = 4 batches x 12 h */
#define QW 48    /* floats per slice row */
#define FC1_BLOCKS 313

// ---------------- CSR build ----------------
__global__ void deg_kernel(const int* __restrict__ row, int* __restrict__ cnt) {
    int e = blockIdx.x * 256 + threadIdx.x;
    if (e < N_EDGES) atomicAdd(&cnt[row[e]], 1);
}

__global__ void dinv_kernel(const int* __restrict__ cnt, float* __restrict__ dinv) {
    int n = blockIdx.x * 256 + threadIdx.x;
    if (n < N_NODES) {
        int d = cnt[n];
        dinv[n] = (d > 0) ? 1.0f / sqrtf((float)d) : 0.0f;
    }
}

__global__ __launch_bounds__(1024) void scan_kernel(const int* __restrict__ cnt,
                                                    int* __restrict__ rowstart) {
    __shared__ int sums[1024];
    int t = threadIdx.x;
    const int per = 10; // 1024*10 >= 10000
    int base = t * per;
    int s = 0;
    for (int i = 0; i < per; i++) { int idx = base + i; if (idx < N_NODES) s += cnt[idx]; }
    sums[t] = s;
    __syncthreads();
    for (int off = 1; off < 1024; off <<= 1) {
        int v = 0;
        if (t >= off) v = sums[t - off];
        __syncthreads();
        sums[t] += v;
        __syncthreads();
    }
    int run = sums[t] - s; // exclusive prefix for this chunk
    for (int i = 0; i < per; i++) {
        int idx = base + i;
        if (idx < N_NODES) { rowstart[idx] = run; run += cnt[idx]; }
    }
    if (t == 1023) rowstart[N_NODES] = run;
}

__global__ void scatter_kernel(const int* __restrict__ row, const int* __restrict__ col,
                               const float* __restrict__ dinv,
                               const int* __restrict__ rowstart, int* __restrict__ cursor,
                               int2* __restrict__ csr_pack) {
    int e = blockIdx.x * 256 + threadIdx.x;
    if (e < N_EDGES) {
        int r = row[e], c = col[e];
        int p = rowstart[r] + atomicAdd(&cursor[r], 1);
        float nrm = -dinv[r] * dinv[c];
        csr_pack[p] = make_int2(c, __float_as_int(nrm));
    }
}

// ---------------- FFT (real part, H=12 cosine transform) ----------------
// x: [B, N, H] b-major.  xf (split layout): [NQ][N][QW], slice q holds b in [4q,4q+4)
__global__ __launch_bounds__(256) void fft_kernel(const float* __restrict__ x,
                                                  float* __restrict__ xf) {
    __shared__ float C[HLEN][HLEN];
    int t = threadIdx.x;
    if (t < HLEN * HLEN) {
        int k = t / HLEN, tt = t % HLEN;
        C[k][tt] = cosf(0.52359877559829887308f * (float)(k * tt)); // pi/6 * k*t
    }
    __syncthreads();
    int tid = blockIdx.x * 256 + t; // tid = n*32 + b
    if (tid >= N_NODES * BATCH) return;
    int n = tid >> 5, b = tid & 31;
    const float* xp = x + (size_t)b * (N_NODES * HLEN) + (size_t)n * HLEN;
    float xr[HLEN];
#pragma unroll
    for (int i = 0; i < HLEN; i++) xr[i] = xp[i];
    int q = b >> 2, bl = b & 3;
    float* o = xf + ((size_t)q * N_NODES + n) * QW + bl * HLEN;
#pragma unroll
    for (int k = 0; k < HLEN; k++) {
        float s = 0.f;
#pragma unroll
        for (int i = 0; i < HLEN; i++) s += xr[i] * C[k][i];
        o[k] = s;
    }
}

// ---------------- k=0 einsum init (split layout): out[n, q-chunk] = T0 @ W0 ----------------
__global__ __launch_bounds__(256) void k0_split_kernel(const float* __restrict__ z,
                                                       float* __restrict__ out,
                                                       const float* __restrict__ w0) {
    __shared__ float zs[4][QW];
    __shared__ float wk[HLEN * G1];
    int t = threadIdx.x;
    int wv = t >> 6, lane = t & 63;
    int bid = blockIdx.x;
    int q = bid & 7;
    int node = (bid >> 3) * 4 + wv;
    for (int i = t; i < HLEN * G1; i += 256) wk[i] = w0[i];
    if (lane < QW) {
        zs[wv][lane] = z[((size_t)q * N_NODES + node) * QW + lane];
    }
    __syncthreads();
    float* op = out + (size_t)node * BG + q * 128;
#pragma unroll
    for (int r = 0; r < 2; r++) {
        int j = lane + 64 * r;
        int bl = j >> 5, f = j & 31;
        const float* zb = &zs[wv][bl * HLEN];
        float s = 0.f;
#pragma unroll
        for (int h = 0; h < HLEN; h++) s += zb[h] * wk[h * G1 + f];
        __builtin_nontemporal_store(s, op + j);
    }
}

// ---------------- fused XCD-split SpMM + per-slice einsum accumulate ----------------
// znext = alpha*(Lt @ zcur) - beta*zprev  (slice q only; blockIdx&7 = q pins slice to XCD)
// out[n, 4q:4q+4, :] += znext[n, slice] @ Wk   (nontemporal RMW; znext stays L2-cached)
__global__ __launch_bounds__(256) void spmm_fused_kernel(
    const float* __restrict__ zcur, const float* __restrict__ zprev,
    float* __restrict__ znext, float* __restrict__ out,
    const int* __restrict__ rowstart, const int2* __restrict__ csr_pack,
    const float* __restrict__ wkg, float alpha, float beta) {
    __shared__ float zs[4][QW];
    __shared__ float wk[HLEN * G1];
    int t = threadIdx.x;
    int wv = t >> 6, lane = t & 63;
    int bid = blockIdx.x;
    int q = bid & 7;
    int node = (bid >> 3) * 4 + wv;
    for (int i = t; i < HLEN * G1; i += 256) wk[i] = wkg[i];

    const float* zq = zcur + (size_t)q * ((size_t)N_NODES * QW);
    if (lane < QW) {
        float acc = 0.f;
        int e0 = rowstart[node], e1 = rowstart[node + 1];
        int e = e0;
        for (; e + 2 <= e1; e += 2) {
            int2 p0 = csr_pack[e];
            int2 p1 = csr_pack[e + 1];
            float z0 = zq[(size_t)p0.x * QW + lane];
            float z1 = zq[(size_t)p1.x * QW + lane];
            acc += __int_as_float(p0.y) * z0 + __int_as_float(p1.y) * z1;
        }
        if (e < e1) {
            int2 p0 = csr_pack[e];
            acc += __int_as_float(p0.y) * zq[(size_t)p0.x * QW + lane];
        }
        size_t idx = ((size_t)q * N_NODES + node) * QW + lane;
        float v = alpha * acc - beta * zprev[idx];
        znext[idx] = v;          // normal (cached) store: next k's gather source
        zs[wv][lane] = v;
    }
    __syncthreads();
    float* op = out + (size_t)node * BG + q * 128;
#pragma unroll
    for (int r = 0; r < 2; r++) {
        int j = lane + 64 * r;
        int bl = j >> 5, f = j & 31;
        const float* zb = &zs[wv][bl * HLEN];
        float s = 0.f;
#pragma unroll
        for (int h = 0; h < HLEN; h++) s += zb[h] * wk[h * G1 + f];
        float cur = __builtin_nontemporal_load(op + j);
        __builtin_nontemporal_store(cur + s, op + j);
    }
}

// ---------------- FC stage 1: per-block partials, atomic-free ----------------
// Block 256: thread t -> (b = t>>3, f-quad = (t&7)*4). 32 nodes per block.
__global__ __launch_bounds__(256) void fc1_kernel(const float* __restrict__ out,
                                                  const float* __restrict__ conv_b,
                                                  const float* __restrict__ fc_w,
                                                  float* __restrict__ partials) {
    int t = threadIdx.x;
    int b = t >> 3;
    int sq = t & 7;
    int f0 = sq * 4;
    float4 cb4 = *(const float4*)(conv_b + f0);

    int n0 = blockIdx.x * 32;
    int n1 = n0 + 32;
    if (n1 > N_NODES) n1 = N_NODES;

    float acc[NCLS];
#pragma unroll
    for (int c = 0; c < NCLS; c++) acc[c] = 0.f;

    for (int n = n0; n < n1; n++) {
        float4 o = *(const float4*)(out + (size_t)n * BG + b * G1 + f0);
        o.x += cb4.x; o.y += cb4.y; o.z += cb4.z; o.w += cb4.w;
        o.x = o.x > 0.f ? o.x : 0.f;
        o.y = o.y > 0.f ? o.y : 0.f;
        o.z = o.z > 0.f ? o.z : 0.f;
        o.w = o.w > 0.f ? o.w : 0.f;
        const float* wp = fc_w + (size_t)n * G1 + f0;
#pragma unroll
        for (int c = 0; c < NCLS; c++) {
            float4 w = *(const float4*)(wp + (size_t)c * (N_NODES * G1));
            acc[c] += o.x * w.x + o.y * w.y + o.z * w.z + o.w * w.w;
        }
    }
#pragma unroll
    for (int c = 0; c < NCLS; c++) {
        float v = acc[c];
        v += __shfl_xor(v, 1);
        v += __shfl_xor(v, 2);
        v += __shfl_xor(v, 4);
        if (sq == 0) partials[(size_t)blockIdx.x * (BATCH * NCLS) + b * NCLS + c] = v;
    }
}

// ---------------- FC stage 2 + log_softmax ----------------
__global__ __launch_bounds__(320) void fc2_kernel(const float* __restrict__ partials,
                                                  const float* __restrict__ fc_b,
                                                  float* __restrict__ outp) {
    __shared__ float lg[BATCH][NCLS];
    int t = threadIdx.x; // 0..319 -> (b,c)
    int b = t / NCLS, c = t % NCLS;
    float a0 = 0.f, a1 = 0.f, a2 = 0.f, a3 = 0.f;
    int i = 0;
    for (; i + 4 <= FC1_BLOCKS; i += 4) {
        a0 += partials[(size_t)(i + 0) * (BATCH * NCLS) + t];
        a1 += partials[(size_t)(i + 1) * (BATCH * NCLS) + t];
        a2 += partials[(size_t)(i + 2) * (BATCH * NCLS) + t];
        a3 += partials[(size_t)(i + 3) * (BATCH * NCLS) + t];
    }
    for (; i < FC1_BLOCKS; i++) a0 += partials[(size_t)i * (BATCH * NCLS) + t];
    lg[b][c] = a0 + a1 + a2 + a3 + fc_b[c];
    __syncthreads();
    if (t < BATCH) {
        float v[NCLS];
        float m = -1e30f;
#pragma unroll
        for (int cc = 0; cc < NCLS; cc++) { v[cc] = lg[t][cc]; m = fmaxf(m, v[cc]); }
        float s = 0.f;
#pragma unroll
        for (int cc = 0; cc < NCLS; cc++) s += expf(v[cc] - m);
        float ls = logf(s);
#pragma unroll
        for (int cc = 0; cc < NCLS; cc++) outp[t * NCLS + cc] = v[cc] - m - ls;
    }
}

extern "C" void kernel_launch(void* const* d_in, const int* in_sizes, int n_in,
                              void* d_out, int out_size, void* d_ws, size_t ws_size,
                              hipStream_t stream) {
    const float* x      = (const float*)d_in[0];
    const int*   ei     = (const int*)d_in[1];
    const float* conv_w = (const float*)d_in[2];
    const float* conv_b = (const float*)d_in[3];
    const float* fc_w   = (const float*)d_in[4];
    const float* fc_b   = (const float*)d_in[5];
    float* outp = (float*)d_out;

    const int* row = ei;
    const int* col = ei + N_EDGES;

    const size_t SLAB = (size_t)N_NODES * BH; // floats per slab (= NQ*N*QW)

    char* ws = (char*)d_ws;
    size_t off = 0;
    auto alloc = [&](size_t bytes) -> void* {
        void* p = ws + off;
        off = (off + bytes + 255) & ~(size_t)255;
        return p;
    };
    // Total footprint ~75 MB (proven budget from R1/R2).
    float* outacc   = (float*)alloc(sizeof(float) * (size_t)N_NODES * BG);   // 41 MB
    float* slabA    = (float*)alloc(sizeof(float) * SLAB);                   // 15.4 MB
    float* slabB    = (float*)alloc(sizeof(float) * SLAB);                   // 15.4 MB
    int*   cnt      = (int*)alloc(sizeof(int) * N_NODES);
    float* dinv     = (float*)alloc(sizeof(float) * N_NODES);
    int*   rowstart = (int*)alloc(sizeof(int) * (N_NODES + 1));
    int*   cursor   = (int*)alloc(sizeof(int) * N_NODES);
    int2*  csr_pack = (int2*)alloc(sizeof(int2) * N_EDGES);                  // 1.28 MB
    float* partials = (float*)alloc(sizeof(float) * FC1_BLOCKS * BATCH * NCLS);

    hipMemsetAsync(cnt, 0, sizeof(int) * N_NODES, stream);
    hipMemsetAsync(cursor, 0, sizeof(int) * N_NODES, stream);

    deg_kernel<<<(N_EDGES + 255) / 256, 256, 0, stream>>>(row, cnt);
    dinv_kernel<<<(N_NODES + 255) / 256, 256, 0, stream>>>(cnt, dinv);
    scan_kernel<<<1, 1024, 0, stream>>>(cnt, rowstart);
    scatter_kernel<<<(N_EDGES + 255) / 256, 256, 0, stream>>>(row, col, dinv, rowstart,
                                                              cursor, csr_pack);

    const int GRID = (N_NODES / 4) * NQ; // 20000 blocks: bid&7 = slice/XCD, bid>>3 = node quad

    // T0 = xf (split layout) -> slabA ; out = T0 @ W0
    fft_kernel<<<(N_NODES * BATCH + 255) / 256, 256, 0, stream>>>(x, slabA);
    k0_split_kernel<<<GRID, 256, 0, stream>>>(slabA, outacc, conv_w);

    // T1 = Lt T0 -> slabB ; out += T1 @ W1
    spmm_fused_kernel<<<GRID, 256, 0, stream>>>(slabA, slabA, slabB, outacc,
                                                rowstart, csr_pack, conv_w + 1 * BH,
                                                1.0f, 0.0f);
    // Tk = 2 Lt T_{k-1} - T_{k-2} (overwrites T_{k-2} slab) ; out += Tk @ Wk
    float* zprev = slabA;
    float* zcur  = slabB;
    for (int k = 2; k < KORD; k++) {
        spmm_fused_kernel<<<GRID, 256, 0, stream>>>(zcur, zprev, zprev, outacc,
                                                    rowstart, csr_pack,
                                                    conv_w + (size_t)k * BH,
                                                    2.0f, 1.0f);
        float* tmp = zprev; zprev = zcur; zcur = tmp;
    }

    fc1_kernel<<<FC1_BLOCKS, 256, 0, stream>>>(outacc, conv_b, fc_w, partials);
    fc2_kernel<<<1, 320, 0, stream>>>(partials, fc_b, outp);
}

// Round 6
// 1666.833 us; speedup vs baseline: 1.2144x; 1.2144x over previous
//
#include <hip/hip_runtime.h>
#include <math.h>

#define N_NODES 10000
#define N_EDGES 160000
#define BATCH 32
#define HLEN 12
#define KORD 25
#define G1 32
#define NCLS 10
#define BH 384   /* BATCH*HLEN */
#define BG 1024  /* BATCH*G1  */
#define NQ 8     /* BH split into 8 slices of 48 = 4 batches x 12 h */
#define QW 48    /* values per slice row */
#define QU 24    /* uints (bf16 pairs) per slice row */
#define FC1_BLOCKS 313

typedef unsigned int uint32;
typedef unsigned short ushort16;

__device__ __forceinline__ float bf16lo(uint32 u) { return __uint_as_float(u << 16); }
__device__ __forceinline__ float bf16hi(uint32 u) { return __uint_as_float(u & 0xffff0000u); }
__device__ __forceinline__ uint32 pack_bf16(float a, float b) {
    uint32 ua = __float_as_uint(a), ub = __float_as_uint(b);
    ua = (ua + 0x7fffu + ((ua >> 16) & 1u)) >> 16;
    ub = (ub + 0x7fffu + ((ub >> 16) & 1u)) & 0xffff0000u;
    return ua | ub;
}
__device__ __forceinline__ ushort16 f2bf(float a) {
    uint32 ua = __float_as_uint(a);
    return (ushort16)((ua + 0x7fffu + ((ua >> 16) & 1u)) >> 16);
}

// ---------------- CSR build ----------------
__global__ void deg_kernel(const int* __restrict__ row, int* __restrict__ cnt) {
    int e = blockIdx.x * 256 + threadIdx.x;
    if (e < N_EDGES) atomicAdd(&cnt[row[e]], 1);
}

__global__ void dinv_kernel(const int* __restrict__ cnt, float* __restrict__ dinv) {
    int n = blockIdx.x * 256 + threadIdx.x;
    if (n < N_NODES) {
        int d = cnt[n];
        dinv[n] = (d > 0) ? 1.0f / sqrtf((float)d) : 0.0f;
    }
}

__global__ __launch_bounds__(1024) void scan_kernel(const int* __restrict__ cnt,
                                                    int* __restrict__ rowstart) {
    __shared__ int sums[1024];
    int t = threadIdx.x;
    const int per = 10;
    int base = t * per;
    int s = 0;
    for (int i = 0; i < per; i++) { int idx = base + i; if (idx < N_NODES) s += cnt[idx]; }
    sums[t] = s;
    __syncthreads();
    for (int off = 1; off < 1024; off <<= 1) {
        int v = 0;
        if (t >= off) v = sums[t - off];
        __syncthreads();
        sums[t] += v;
        __syncthreads();
    }
    int run = sums[t] - s;
    for (int i = 0; i < per; i++) {
        int idx = base + i;
        if (idx < N_NODES) { rowstart[idx] = run; run += cnt[idx]; }
    }
    if (t == 1023) rowstart[N_NODES] = run;
}

__global__ void scatter_kernel(const int* __restrict__ row, const int* __restrict__ col,
                               const float* __restrict__ dinv,
                               const int* __restrict__ rowstart, int* __restrict__ cursor,
                               int2* __restrict__ csr_pack) {
    int e = blockIdx.x * 256 + threadIdx.x;
    if (e < N_EDGES) {
        int r = row[e], c = col[e];
        int p = rowstart[r] + atomicAdd(&cursor[r], 1);
        float nrm = -dinv[r] * dinv[c];
        csr_pack[p] = make_int2(c, __float_as_int(nrm));
    }
}

// ---------------- FFT (real part, H=12 cosine transform) ----------------
// x: [B, N, H] b-major. xf (bf16 split layout): [NQ][N][QW] ushorts.
__global__ __launch_bounds__(256) void fft_kernel(const float* __restrict__ x,
                                                  ushort16* __restrict__ xf) {
    __shared__ float C[HLEN][HLEN];
    int t = threadIdx.x;
    if (t < HLEN * HLEN) {
        int k = t / HLEN, tt = t % HLEN;
        C[k][tt] = cosf(0.52359877559829887308f * (float)(k * tt)); // pi/6 * k*t
    }
    __syncthreads();
    int tid = blockIdx.x * 256 + t; // tid = n*32 + b
    if (tid >= N_NODES * BATCH) return;
    int n = tid >> 5, b = tid & 31;
    const float* xp = x + (size_t)b * (N_NODES * HLEN) + (size_t)n * HLEN;
    float xr[HLEN];
#pragma unroll
    for (int i = 0; i < HLEN; i++) xr[i] = xp[i];
    int q = b >> 2, bl = b & 3;
    ushort16* o = xf + ((size_t)q * N_NODES + n) * QW + bl * HLEN;
#pragma unroll
    for (int k = 0; k < HLEN; k++) {
        float s = 0.f;
#pragma unroll
        for (int i = 0; i < HLEN; i++) s += xr[i] * C[k][i];
        o[k] = f2bf(s);
    }
}

// ---------------- k=0 einsum init (bf16 split layout) ----------------
__global__ __launch_bounds__(256) void k0_split_kernel(const uint32* __restrict__ z,
                                                       float* __restrict__ out,
                                                       const float* __restrict__ w0) {
    __shared__ float zs[4][QW];
    __shared__ float wk[HLEN * G1];
    int t = threadIdx.x;
    int wv = t >> 6, lane = t & 63;
    int bid = blockIdx.x;
    int q = bid & 7;
    int node = (bid >> 3) * 4 + wv;
    for (int i = t; i < HLEN * G1; i += 256) wk[i] = w0[i];
    if (lane < QU) {
        uint32 u = z[((size_t)q * N_NODES + node) * QU + lane];
        zs[wv][2 * lane]     = bf16lo(u);
        zs[wv][2 * lane + 1] = bf16hi(u);
    }
    __syncthreads();
    float* op = out + (size_t)node * BG + q * 128;
#pragma unroll
    for (int r = 0; r < 2; r++) {
        int j = lane + 64 * r;
        int bl = j >> 5, f = j & 31;
        const float* zb = &zs[wv][bl * HLEN];
        float s = 0.f;
#pragma unroll
        for (int h = 0; h < HLEN; h++) s += zb[h] * wk[h * G1 + f];
        op[j] = s;
    }
}

// ---------------- fused XCD-split SpMM (bf16) + per-slice einsum accumulate ----------------
// znext = alpha*(Lt @ zcur) - beta*zprev (slice q; bid&7 = q attempts XCD-pinning).
// Edge-pair gather: lanes 0-23 edge e, lanes 24-47 edge e+1, uint = 2 bf16 per lane.
// out[n, 4q:4q+4, :] += T_k slice @ Wk (plain cached RMW -> L3).
__global__ __launch_bounds__(256) void spmm_fused_kernel(
    const uint32* __restrict__ zcur, const uint32* __restrict__ zprev,
    uint32* __restrict__ znext, float* __restrict__ out,
    const int* __restrict__ rowstart, const int2* __restrict__ csr_pack,
    const float* __restrict__ wkg, float alpha, float beta) {
    __shared__ float zs[4][QW];
    __shared__ float wk[HLEN * G1];
    int t = threadIdx.x;
    int wv = t >> 6, lane = t & 63;
    int bid = blockIdx.x;
    int q = bid & 7;
    int node = (bid >> 3) * 4 + wv;
    for (int i = t; i < HLEN * G1; i += 256) wk[i] = wkg[i];

    const uint32* zq = zcur + (size_t)q * ((size_t)N_NODES * QU);
    int g  = (lane >= 24) ? 1 : 0;
    int li = lane - g * 24;
    float acc0 = 0.f, acc1 = 0.f;
    int e0 = rowstart[node], e1 = rowstart[node + 1];
    if (lane < 48) {
        int e = e0;
        for (; e + 2 <= e1; e += 2) {
            int2 p = csr_pack[e + g];
            float nrm = __int_as_float(p.y);
            uint32 u = zq[(size_t)p.x * QU + li];
            acc0 += nrm * bf16lo(u);
            acc1 += nrm * bf16hi(u);
        }
        if (e < e1 && g == 0) {
            int2 p = csr_pack[e];
            float nrm = __int_as_float(p.y);
            uint32 u = zq[(size_t)p.x * QU + li];
            acc0 += nrm * bf16lo(u);
            acc1 += nrm * bf16hi(u);
        }
    }
    // fold group-1 partials into group-0 lanes
    float o0 = __shfl(acc0, li + 24);
    float o1 = __shfl(acc1, li + 24);
    if (lane < 24) {
        acc0 += o0;
        acc1 += o1;
        size_t idx = ((size_t)q * N_NODES + node) * QU + li;
        uint32 pu = zprev[idx];
        float v0 = alpha * acc0 - beta * bf16lo(pu);
        float v1 = alpha * acc1 - beta * bf16hi(pu);
        znext[idx] = pack_bf16(v0, v1);
        zs[wv][2 * li]     = v0;
        zs[wv][2 * li + 1] = v1;
    }
    __syncthreads();
    float* op = out + (size_t)node * BG + q * 128;
#pragma unroll
    for (int r = 0; r < 2; r++) {
        int j = lane + 64 * r;
        int bl = j >> 5, f = j & 31;
        const float* zb = &zs[wv][bl * HLEN];
        float s = 0.f;
#pragma unroll
        for (int h = 0; h < HLEN; h++) s += zb[h] * wk[h * G1 + f];
        op[j] += s;
    }
}

// ---------------- FC stage 1: per-block partials, atomic-free ----------------
__global__ __launch_bounds__(256) void fc1_kernel(const float* __restrict__ out,
                                                  const float* __restrict__ conv_b,
                                                  const float* __restrict__ fc_w,
                                                  float* __restrict__ partials) {
    int t = threadIdx.x;
    int b = t >> 3;
    int sq = t & 7;
    int f0 = sq * 4;
    float4 cb4 = *(const float4*)(conv_b + f0);

    int n0 = blockIdx.x * 32;
    int n1 = n0 + 32;
    if (n1 > N_NODES) n1 = N_NODES;

    float acc[NCLS];
#pragma unroll
    for (int c = 0; c < NCLS; c++) acc[c] = 0.f;

    for (int n = n0; n < n1; n++) {
        float4 o = *(const float4*)(out + (size_t)n * BG + b * G1 + f0);
        o.x += cb4.x; o.y += cb4.y; o.z += cb4.z; o.w += cb4.w;
        o.x = o.x > 0.f ? o.x : 0.f;
        o.y = o.y > 0.f ? o.y : 0.f;
        o.z = o.z > 0.f ? o.z : 0.f;
        o.w = o.w > 0.f ? o.w : 0.f;
        const float* wp = fc_w + (size_t)n * G1 + f0;
#pragma unroll
        for (int c = 0; c < NCLS; c++) {
            float4 w = *(const float4*)(wp + (size_t)c * (N_NODES * G1));
            acc[c] += o.x * w.x + o.y * w.y + o.z * w.z + o.w * w.w;
        }
    }
#pragma unroll
    for (int c = 0; c < NCLS; c++) {
        float v = acc[c];
        v += __shfl_xor(v, 1);
        v += __shfl_xor(v, 2);
        v += __shfl_xor(v, 4);
        if (sq == 0) partials[(size_t)blockIdx.x * (BATCH * NCLS) + b * NCLS + c] = v;
    }
}

// ---------------- FC stage 2 + log_softmax ----------------
__global__ __launch_bounds__(320) void fc2_kernel(const float* __restrict__ partials,
                                                  const float* __restrict__ fc_b,
                                                  float* __restrict__ outp) {
    __shared__ float lg[BATCH][NCLS];
    int t = threadIdx.x; // 0..319 -> (b,c)
    int b = t / NCLS, c = t % NCLS;
    float a0 = 0.f, a1 = 0.f, a2 = 0.f, a3 = 0.f;
    int i = 0;
    for (; i + 4 <= FC1_BLOCKS; i += 4) {
        a0 += partials[(size_t)(i + 0) * (BATCH * NCLS) + t];
        a1 += partials[(size_t)(i + 1) * (BATCH * NCLS) + t];
        a2 += partials[(size_t)(i + 2) * (BATCH * NCLS) + t];
        a3 += partials[(size_t)(i + 3) * (BATCH * NCLS) + t];
    }
    for (; i < FC1_BLOCKS; i++) a0 += partials[(size_t)i * (BATCH * NCLS) + t];
    lg[b][c] = a0 + a1 + a2 + a3 + fc_b[c];
    __syncthreads();
    if (t < BATCH) {
        float v[NCLS];
        float m = -1e30f;
#pragma unroll
        for (int cc = 0; cc < NCLS; cc++) { v[cc] = lg[t][cc]; m = fmaxf(m, v[cc]); }
        float s = 0.f;
#pragma unroll
        for (int cc = 0; cc < NCLS; cc++) s += expf(v[cc] - m);
        float ls = logf(s);
#pragma unroll
        for (int cc = 0; cc < NCLS; cc++) outp[t * NCLS + cc] = v[cc] - m - ls;
    }
}

extern "C" void kernel_launch(void* const* d_in, const int* in_sizes, int n_in,
                              void* d_out, int out_size, void* d_ws, size_t ws_size,
                              hipStream_t stream) {
    const float* x      = (const float*)d_in[0];
    const int*   ei     = (const int*)d_in[1];
    const float* conv_w = (const float*)d_in[2];
    const float* conv_b = (const float*)d_in[3];
    const float* fc_w   = (const float*)d_in[4];
    const float* fc_b   = (const float*)d_in[5];
    float* outp = (float*)d_out;

    const int* row = ei;
    const int* col = ei + N_EDGES;

    const size_t SLAB_U = (size_t)NQ * N_NODES * QU; // uints per bf16 slab

    char* ws = (char*)d_ws;
    size_t off = 0;
    auto alloc = [&](size_t bytes) -> void* {
        void* p = ws + off;
        off = (off + bytes + 255) & ~(size_t)255;
        return p;
    };
    // footprint ~58 MB (< proven 75 MB budget)
    float*  outacc   = (float*)alloc(sizeof(float) * (size_t)N_NODES * BG);  // 41 MB
    uint32* slabA    = (uint32*)alloc(sizeof(uint32) * SLAB_U);              // 7.7 MB
    uint32* slabB    = (uint32*)alloc(sizeof(uint32) * SLAB_U);              // 7.7 MB
    int*    cnt      = (int*)alloc(sizeof(int) * N_NODES);
    float*  dinv     = (float*)alloc(sizeof(float) * N_NODES);
    int*    rowstart = (int*)alloc(sizeof(int) * (N_NODES + 1));
    int*    cursor   = (int*)alloc(sizeof(int) * N_NODES);
    int2*   csr_pack = (int2*)alloc(sizeof(int2) * N_EDGES);                 // 1.28 MB
    float*  partials = (float*)alloc(sizeof(float) * FC1_BLOCKS * BATCH * NCLS);

    hipMemsetAsync(cnt, 0, sizeof(int) * N_NODES, stream);
    hipMemsetAsync(cursor, 0, sizeof(int) * N_NODES, stream);

    deg_kernel<<<(N_EDGES + 255) / 256, 256, 0, stream>>>(row, cnt);
    dinv_kernel<<<(N_NODES + 255) / 256, 256, 0, stream>>>(cnt, dinv);
    scan_kernel<<<1, 1024, 0, stream>>>(cnt, rowstart);
    scatter_kernel<<<(N_EDGES + 255) / 256, 256, 0, stream>>>(row, col, dinv, rowstart,
                                                              cursor, csr_pack);

    const int GRID = (N_NODES / 4) * NQ; // 20000 blocks: bid&7 = slice, bid>>3 = node quad

    // T0 = xf (bf16 split layout) -> slabA ; out = T0 @ W0
    fft_kernel<<<(N_NODES * BATCH + 255) / 256, 256, 0, stream>>>(x, (ushort16*)slabA);
    k0_split_kernel<<<GRID, 256, 0, stream>>>(slabA, outacc, conv_w);

    // T1 = Lt T0 -> slabB ; out += T1 @ W1
    spmm_fused_kernel<<<GRID, 256, 0, stream>>>(slabA, slabA, slabB, outacc,
                                                rowstart, csr_pack, conv_w + 1 * BH,
                                                1.0f, 0.0f);
    // Tk = 2 Lt T_{k-1} - T_{k-2} (overwrites T_{k-2} slab) ; out += Tk @ Wk
    uint32* zprev = slabA;
    uint32* zcur  = slabB;
    for (int k = 2; k < KORD; k++) {
        spmm_fused_kernel<<<GRID, 256, 0, stream>>>(zcur, zprev, zprev, outacc,
                                                    rowstart, csr_pack,
                                                    conv_w + (size_t)k * BH,
                                                    2.0f, 1.0f);
        uint32* tmp = zprev; zprev = zcur; zcur = tmp;
    }

    fc1_kernel<<<FC1_BLOCKS, 256, 0, stream>>>(outacc, conv_b, fc_w, partials);
    fc2_kernel<<<1, 320, 0, stream>>>(partials, fc_b, outp);
}